// Round 5
// baseline (381.239 us; speedup 1.0000x reference)
//
#include <hip/hip_runtime.h>
#include <math.h>

// Problem constants
#define DIM   384
#define NQKV  1152
#define IMG   56
#define ROWS_PER_B (IMG*IMG)           // 3136 pixels per batch image

typedef unsigned short u16;
typedef __attribute__((ext_vector_type(4))) float f32x4;
typedef __attribute__((ext_vector_type(8))) short s16x8;

__device__ __forceinline__ u16 f2b(float f) {           // fp32 -> bf16 RNE
    unsigned u = __float_as_uint(f);
    return (u16)((u + 0x7fffu + ((u >> 16) & 1u)) >> 16);
}
__device__ __forceinline__ float b2f(u16 h) {
    return __uint_as_float(((unsigned)h) << 16);
}

// ---------------------------------------------------------------------------
// Kernel 1: relative sinusoidal embedding table (49x49), bit-faithful to numpy
// arange fill: delta = fl(fl(1+1/7)-1);  x[i] = fl(1 + fl(i*delta)).
// delta != fl(1/7) (off by 2^-54) and the .astype(int32) trunc is
// discontinuous at multiples of 7, so the exact rounding sequence matters.
// DO NOT TOUCH — verified passing in Round 3.
// ---------------------------------------------------------------------------
__global__ __launch_bounds__(256) void emb_init_kernel(float* __restrict__ emb) {
    int idx = blockIdx.x * 256 + threadIdx.x;
    if (idx >= 49 * 49) return;
    int q = idx / 49, k = idx % 49;

    const double step  = 1.0 / 7.0;
    const double delta = __dsub_rn(__dadd_rn(1.0, step), 1.0);
    double xk = __dadd_rn(1.0, __dmul_rn((double)k, delta));
    double xq = __dadd_rn(1.0, __dmul_rn((double)q, delta));
    int xi = (int)__dsub_rn(xk, xq);
    int yi = (k % 7) - (q % 7);

    int r = xi % 13; if (r < 0) r += 13;
    int c = yi % 13; if (c < 0) c += 13;

    const float scl = (float)(-0.7084877209212449);      // -log(10000)/13
    float val;
    if ((c & 1) == 0) val = sinf((float)r * expf((float)c * scl));
    else              val = cosf((float)r * expf((float)(c - 1) * scl));
    emb[idx] = val;
}

// ---------------------------------------------------------------------------
// Conversion kernels
// ---------------------------------------------------------------------------
__global__ __launch_bounds__(256) void cvt_f32_bf16(
    const float* __restrict__ in, u16* __restrict__ out, int n4) {
    int i = blockIdx.x * 256 + threadIdx.x;
    if (i >= n4) return;
    float4 v = ((const float4*)in)[i];
    ushort4 o;
    o.x = f2b(v.x); o.y = f2b(v.y); o.z = f2b(v.z); o.w = f2b(v.w);
    ((ushort4*)out)[i] = o;
}

// w [R][C] fp32  ->  wt [C][R] bf16   (tiny, launched once)
__global__ __launch_bounds__(256) void cvt_transpose_bf16(
    const float* __restrict__ w, u16* __restrict__ wt, int R, int C) {
    int i = blockIdx.x * 256 + threadIdx.x;
    if (i >= R * C) return;
    int r = i / C, c = i % C;
    wt[(size_t)c * R + r] = f2b(w[i]);
}

// ---------------------------------------------------------------------------
// MFMA bf16 GEMM: C[M][N] = A[M][K] @ Bt[N][K]^T + bias.
// 128x128 tile, BK=32, 256 threads = 4 waves, each wave a 64x64 sub-tile
// (4x4 fragments of 16x16x32). LDS [128][40] bf16 (pad -> 2-way conflicts,
// free per m136). C/D layout: col = lane&15, row = (lane>>4)*4 + reg (m89).
// MODE 0: bf16 output (QKV, N=1152 interleaved (ch,comp) natural order).
// MODE 1: fp32 output + bias (final projection).
// Requires M%128==0, N%128==0, K%32==0.
// ---------------------------------------------------------------------------
template <int MODE>
__global__ __launch_bounds__(256) void mfma_gemm(
    const u16* __restrict__ A, const u16* __restrict__ Bt,
    const float* __restrict__ bias,
    u16* __restrict__ outb, float* __restrict__ outf,
    int N, int K)
{
    __shared__ __align__(16) u16 As[128][40];
    __shared__ __align__(16) u16 Bs[128][40];

    const int tid  = threadIdx.x;
    const int lane = tid & 63;
    const int wid  = tid >> 6;
    const int wr   = wid >> 1, wc = wid & 1;     // wave -> 64x64 quadrant
    const int l15  = lane & 15, l4 = lane >> 4;
    const int bm = blockIdx.y, bn = blockIdx.x;

    // staging: thread t covers rows (t>>2) and (t>>2)+64, k-span (t&3)*8..+7
    const int srow = tid >> 2;
    const int sk   = (tid & 3) * 8;

    const u16* Ap = A  + (size_t)(bm * 128 + srow) * K + sk;
    const u16* Bp = Bt + (size_t)(bn * 128 + srow) * K + sk;

    f32x4 acc[4][4] = {};

    for (int kt = 0; kt < K; kt += 32) {
        s16x8 a0 = *(const s16x8*)(Ap + kt);
        s16x8 a1 = *(const s16x8*)(Ap + (size_t)64 * K + kt);
        s16x8 b0 = *(const s16x8*)(Bp + kt);
        s16x8 b1 = *(const s16x8*)(Bp + (size_t)64 * K + kt);
        __syncthreads();                       // prev-iter LDS reads done
        *(s16x8*)&As[srow][sk]      = a0;
        *(s16x8*)&As[srow + 64][sk] = a1;
        *(s16x8*)&Bs[srow][sk]      = b0;
        *(s16x8*)&Bs[srow + 64][sk] = b1;
        __syncthreads();

        s16x8 af[4], bf[4];
        #pragma unroll
        for (int m = 0; m < 4; ++m)
            af[m] = *(const s16x8*)&As[wr * 64 + m * 16 + l15][l4 * 8];
        #pragma unroll
        for (int n = 0; n < 4; ++n)
            bf[n] = *(const s16x8*)&Bs[wc * 64 + n * 16 + l15][l4 * 8];
        #pragma unroll
        for (int m = 0; m < 4; ++m)
            #pragma unroll
            for (int n = 0; n < 4; ++n)
                acc[m][n] = __builtin_amdgcn_mfma_f32_16x16x32_bf16(
                    af[m], bf[n], acc[m][n], 0, 0, 0);
    }

    const int grow0 = bm * 128 + wr * 64;
    const int gcol0 = bn * 128 + wc * 64;
    #pragma unroll
    for (int m = 0; m < 4; ++m) {
        #pragma unroll
        for (int n = 0; n < 4; ++n) {
            int col = gcol0 + n * 16 + l15;
            float bz = bias[col];
            #pragma unroll
            for (int r = 0; r < 4; ++r) {
                int row = grow0 + m * 16 + l4 * 4 + r;
                float v = acc[m][n][r] + bz;
                if constexpr (MODE == 0)
                    outb[(size_t)row * N + col] = f2b(v);
                else
                    outf[(size_t)row * N + col] = v;
            }
        }
    }
}

// ---------------------------------------------------------------------------
// Kernel 3: windowed attention. One block per (b_local, head, wh, ww).
// qkv is bf16 [rows][1152] with column gc = ch*3 + comp (GEMM-natural order).
// Gathers with roll(-4,-4) fused; writes att bf16 [rows][384] with roll(+3,+3).
// ---------------------------------------------------------------------------
__global__ __launch_bounds__(256) void attn_kernel(
    const u16* __restrict__ qkv, const float* __restrict__ emb,
    u16* __restrict__ att)
{
    __shared__ float Qs[49][33];
    __shared__ float Ks[49][33];
    __shared__ float Vs[49][33];
    __shared__ float S[49][49];

    const int blk = blockIdx.x;
    const int bw = blk & 7;
    const int bh = (blk >> 3) & 7;
    const int n  = (blk >> 6) % 12;
    const int b  = blk / 768;            // local batch within chunk
    const int tid = threadIdx.x;

    for (int i = tid; i < 49 * 32; i += 256) {
        int pix = i >> 5, e = i & 31;
        int m1 = pix / 7, m2 = pix % 7;
        int gr = (bh * 7 + m1 + 4) % IMG;
        int gc = (bw * 7 + m2 + 4) % IMG;
        size_t base = ((size_t)(b * IMG + gr) * IMG + gc) * NQKV + (size_t)(n * 32 + e) * 3;
        Qs[pix][e] = b2f(qkv[base + 0]);
        Ks[pix][e] = b2f(qkv[base + 1]);
        Vs[pix][e] = b2f(qkv[base + 2]);
    }
    __syncthreads();

    const float scale = 0.17677669529663687f;   // 1/sqrt(32)
    const bool rowm = (bh == 7), colm = (bw == 7);
    for (int s = tid; s < 49 * 49; s += 256) {
        int q = s / 49, k = s % 49;
        float acc = 0.f;
        #pragma unroll
        for (int e = 0; e < 32; ++e) acc += Qs[q][e] * Ks[k][e];
        float v = acc * scale + emb[s];
        if (rowm && ((q >= 28) != (k >= 28))) v = -INFINITY;
        if (colm && ((q % 7 >= 4) != (k % 7 >= 4))) v = -INFINITY;
        S[q][k] = v;
    }
    __syncthreads();

    if (tid < 49) {
        float m = -INFINITY;
        for (int k = 0; k < 49; ++k) m = fmaxf(m, S[tid][k]);
        float sum = 0.f;
        for (int k = 0; k < 49; ++k) {
            float p = expf(S[tid][k] - m);
            S[tid][k] = p;
            sum += p;
        }
        float inv = 1.f / sum;
        for (int k = 0; k < 49; ++k) S[tid][k] *= inv;
    }
    __syncthreads();

    for (int i = tid; i < 49 * 32; i += 256) {
        int q = i >> 5, e = i & 31;
        float acc = 0.f;
        for (int k = 0; k < 49; ++k) acc += S[q][k] * Vs[k][e];
        int rp = bh * 7 + q / 7, cp = bw * 7 + q % 7;
        int fr = (rp + 3) % IMG, fc = (cp + 3) % IMG;
        att[((size_t)(b * IMG + fr) * IMG + fc) * DIM + n * 32 + e] = f2b(acc);
    }
}

// ---------------------------------------------------------------------------
extern "C" void kernel_launch(void* const* d_in, const int* in_sizes, int n_in,
                              void* d_out, int out_size, void* d_ws, size_t ws_size,
                              hipStream_t stream) {
    const float* x     = (const float*)d_in[0];
    const float* w_qkv = (const float*)d_in[1];
    const float* b_qkv = (const float*)d_in[2];
    const float* w_out = (const float*)d_in[3];
    const float* b_out = (const float*)d_in[4];
    float* out = (float*)d_out;

    char* wsp = (char*)d_ws;
    float* emb   = (float*)wsp;                                  // 16 KB slot
    u16*   wqkvt = (u16*)(wsp + 16384);                          // [1152][384]
    u16*   woutt = (u16*)(wsp + 16384 + 884736);                 // [384][384]
    const size_t fixed = 16384 + 884736 + 294912;                // 1,196,032 B

    // per-batch chunk cost (bytes): xb + qkv + att, all bf16
    const size_t perb = (size_t)ROWS_PER_B * (DIM + NQKV + DIM) * 2; // 12,042,240
    int nb = 16;
    while (nb > 2 && fixed + (size_t)nb * perb > ws_size) nb >>= 1;  // nb even (M%128)

    u16* xb   = (u16*)(wsp + fixed);
    u16* qkvb = xb   + (size_t)nb * ROWS_PER_B * DIM;
    u16* attb = qkvb + (size_t)nb * ROWS_PER_B * NQKV;

    emb_init_kernel<<<10, 256, 0, stream>>>(emb);
    cvt_transpose_bf16<<<(384 * 1152 + 255) / 256, 256, 0, stream>>>(w_qkv, wqkvt, 384, 1152);
    cvt_transpose_bf16<<<(384 * 384 + 255) / 256, 256, 0, stream>>>(w_out, woutt, 384, 384);

    for (int b0 = 0; b0 < 16; b0 += nb) {
        const int rows = nb * ROWS_PER_B;
        const float* xa = x + (size_t)b0 * ROWS_PER_B * DIM;

        cvt_f32_bf16<<<(rows * DIM / 4 + 255) / 256, 256, 0, stream>>>(
            xa, xb, rows * DIM / 4);

        mfma_gemm<0><<<dim3(NQKV / 128, rows / 128), 256, 0, stream>>>(
            xb, wqkvt, b_qkv, qkvb, nullptr, NQKV, DIM);

        attn_kernel<<<nb * 768, 256, 0, stream>>>(qkvb, emb, attb);

        mfma_gemm<1><<<dim3(DIM / 128, rows / 128), 256, 0, stream>>>(
            attb, woutt, b_out, nullptr, out + (size_t)b0 * ROWS_PER_B * DIM, DIM, DIM);
    }
}

// Round 6
// 248.780 us; speedup vs baseline: 1.5324x; 1.5324x over previous
//
#include <hip/hip_runtime.h>
#include <math.h>

// Problem constants
#define DIM   384
#define NQKV  1152
#define IMG   56
#define ROWS_PER_B (IMG*IMG)           // 3136 pixels per batch image

typedef unsigned short u16;
typedef __attribute__((ext_vector_type(4))) float f32x4;
typedef __attribute__((ext_vector_type(8))) short s16x8;

__device__ __forceinline__ u16 f2b(float f) {           // fp32 -> bf16 RNE
    unsigned u = __float_as_uint(f);
    return (u16)((u + 0x7fffu + ((u >> 16) & 1u)) >> 16);
}
__device__ __forceinline__ float b2f(u16 h) {
    return __uint_as_float(((unsigned)h) << 16);
}

// ---------------------------------------------------------------------------
// Kernel 1: masked relative-embedding table, 4 variants [4][64][64]:
//   v bit0: row-shift mask active (bh==7), bit1: col-shift mask (bw==7).
// Pad (q>=49 || k>=49) = -inf so MFMA's padded K-columns softmax to zero.
// Base sinusoid math is bit-faithful to numpy arange fill (verified R3):
// delta = fl(fl(1+1/7)-1);  x[i] = fl(1 + fl(i*delta));  xi = trunc diff.
// ---------------------------------------------------------------------------
__global__ __launch_bounds__(256) void emb4_init_kernel(float* __restrict__ emb4) {
    int idx = blockIdx.x * 256 + threadIdx.x;
    if (idx >= 64 * 64) return;
    int q = idx >> 6, k = idx & 63;

    bool pad = (q >= 49) || (k >= 49);
    float base = 0.f;
    if (!pad) {
        const double step  = 1.0 / 7.0;
        const double delta = __dsub_rn(__dadd_rn(1.0, step), 1.0);
        double xk = __dadd_rn(1.0, __dmul_rn((double)k, delta));
        double xq = __dadd_rn(1.0, __dmul_rn((double)q, delta));
        int xi = (int)__dsub_rn(xk, xq);
        int yi = (k % 7) - (q % 7);
        int r = xi % 13; if (r < 0) r += 13;
        int c = yi % 13; if (c < 0) c += 13;
        const float scl = (float)(-0.7084877209212449);  // -log(10000)/13
        if ((c & 1) == 0) base = sinf((float)r * expf((float)c * scl));
        else              base = cosf((float)r * expf((float)(c - 1) * scl));
    }
    bool rmask = !pad && ((q >= 28) != (k >= 28));
    bool cmask = !pad && ((q % 7 >= 4) != (k % 7 >= 4));
    #pragma unroll
    for (int v = 0; v < 4; ++v) {
        float val = base;
        if (pad || ((v & 1) && rmask) || ((v & 2) && cmask)) val = -INFINITY;
        emb4[v * 4096 + idx] = val;
    }
}

// ---------------------------------------------------------------------------
// Conversion kernels (unchanged, verified)
// ---------------------------------------------------------------------------
__global__ __launch_bounds__(256) void cvt_f32_bf16(
    const float* __restrict__ in, u16* __restrict__ out, int n4) {
    int i = blockIdx.x * 256 + threadIdx.x;
    if (i >= n4) return;
    float4 v = ((const float4*)in)[i];
    ushort4 o;
    o.x = f2b(v.x); o.y = f2b(v.y); o.z = f2b(v.z); o.w = f2b(v.w);
    ((ushort4*)out)[i] = o;
}

__global__ __launch_bounds__(256) void cvt_transpose_bf16(
    const float* __restrict__ w, u16* __restrict__ wt, int R, int C) {
    int i = blockIdx.x * 256 + threadIdx.x;
    if (i >= R * C) return;
    int r = i / C, c = i % C;
    wt[(size_t)c * R + r] = f2b(w[i]);
}

// ---------------------------------------------------------------------------
// MFMA bf16 GEMM (unchanged, verified R5): C[M][N] = A[M][K] @ Bt[N][K]^T + b.
// ---------------------------------------------------------------------------
template <int MODE>
__global__ __launch_bounds__(256) void mfma_gemm(
    const u16* __restrict__ A, const u16* __restrict__ Bt,
    const float* __restrict__ bias,
    u16* __restrict__ outb, float* __restrict__ outf,
    int N, int K)
{
    __shared__ __align__(16) u16 As[128][40];
    __shared__ __align__(16) u16 Bs[128][40];

    const int tid  = threadIdx.x;
    const int lane = tid & 63;
    const int wid  = tid >> 6;
    const int wr   = wid >> 1, wc = wid & 1;
    const int l15  = lane & 15, l4 = lane >> 4;
    const int bm = blockIdx.y, bn = blockIdx.x;

    const int srow = tid >> 2;
    const int sk   = (tid & 3) * 8;

    const u16* Ap = A  + (size_t)(bm * 128 + srow) * K + sk;
    const u16* Bp = Bt + (size_t)(bn * 128 + srow) * K + sk;

    f32x4 acc[4][4] = {};

    for (int kt = 0; kt < K; kt += 32) {
        s16x8 a0 = *(const s16x8*)(Ap + kt);
        s16x8 a1 = *(const s16x8*)(Ap + (size_t)64 * K + kt);
        s16x8 b0 = *(const s16x8*)(Bp + kt);
        s16x8 b1 = *(const s16x8*)(Bp + (size_t)64 * K + kt);
        __syncthreads();
        *(s16x8*)&As[srow][sk]      = a0;
        *(s16x8*)&As[srow + 64][sk] = a1;
        *(s16x8*)&Bs[srow][sk]      = b0;
        *(s16x8*)&Bs[srow + 64][sk] = b1;
        __syncthreads();

        s16x8 af[4], bf[4];
        #pragma unroll
        for (int m = 0; m < 4; ++m)
            af[m] = *(const s16x8*)&As[wr * 64 + m * 16 + l15][l4 * 8];
        #pragma unroll
        for (int n = 0; n < 4; ++n)
            bf[n] = *(const s16x8*)&Bs[wc * 64 + n * 16 + l15][l4 * 8];
        #pragma unroll
        for (int m = 0; m < 4; ++m)
            #pragma unroll
            for (int n = 0; n < 4; ++n)
                acc[m][n] = __builtin_amdgcn_mfma_f32_16x16x32_bf16(
                    af[m], bf[n], acc[m][n], 0, 0, 0);
    }

    const int grow0 = bm * 128 + wr * 64;
    const int gcol0 = bn * 128 + wc * 64;
    #pragma unroll
    for (int m = 0; m < 4; ++m) {
        #pragma unroll
        for (int n = 0; n < 4; ++n) {
            int col = gcol0 + n * 16 + l15;
            float bz = bias[col];
            #pragma unroll
            for (int r = 0; r < 4; ++r) {
                int row = grow0 + m * 16 + l4 * 4 + r;
                float v = acc[m][n][r] + bz;
                if constexpr (MODE == 0)
                    outb[(size_t)row * N + col] = f2b(v);
                else
                    outf[(size_t)row * N + col] = v;
            }
        }
    }
}

// ---------------------------------------------------------------------------
// Kernel 3: MFMA windowed attention.
// Block = 4 waves = 4 heads of one (b, wh, ww) window; 3 blocks per window.
// Per wave (private LDS arena, 14848 B):
//   Q [64][40] bf16 @ 0      (5120 B)   k-dim = e (32)
//   K [64][40] bf16 @ 2560   (5120 B)
//   P [64][72] bf16 @ 0      (9216 B, overlays Q+K after fragments in regs)
//   Vt[32][72] bf16 @ 5120   (4608 B)   Vt[e][k_pix]
// S^T = mfma(K, Q): lane l15 = q-col, rows k = m*16 + l4*4 + r.
// Softmax: 16 in-reg values + shfl_xor(16,32) over l4 groups. P normalized,
// bf16, to LDS. PV = mfma(P, Vt) over K=64 (2 k-halves). roll(+3,+3) fused.
// ---------------------------------------------------------------------------
__global__ __launch_bounds__(256) void attn_mfma_kernel(
    const u16* __restrict__ qkv, const float* __restrict__ emb4,
    u16* __restrict__ att)
{
    __shared__ __align__(16) u16 sh[4][7424];

    const int tid  = threadIdx.x;
    const int lane = tid & 63;
    const int wid  = tid >> 6;
    const int l15  = lane & 15, l4 = lane >> 4;

    const int blk = blockIdx.x;
    const int hg  = blk % 3;
    const int win = (blk / 3) & 63;
    const int b   = blk / 192;
    const int bw  = win & 7, bh = win >> 3;
    const int head = hg * 4 + wid;

    u16* Q  = sh[wid];              // [64][40]
    u16* Kk = sh[wid] + 2560;       // [64][40]
    u16* P  = sh[wid];              // [64][72] overlay
    u16* Vt = sh[wid] + 5120;       // [32][72]

    // ---- stage Q/K/V (roll(-4,-4) fused, rows 49..63 zeroed) ----
    for (int i = lane; i < 64 * 32; i += 64) {
        int pix = i >> 5, e = i & 31;
        u16 qv = 0, kv = 0, vv = 0;
        if (pix < 49) {
            int gr = (bh * 7 + pix / 7 + 4) % IMG;
            int gc = (bw * 7 + pix % 7 + 4) % IMG;
            size_t base = ((size_t)(b * IMG + gr) * IMG + gc) * NQKV
                        + (size_t)(head * 32 + e) * 3;
            qv = qkv[base]; kv = qkv[base + 1]; vv = qkv[base + 2];
        }
        Q[pix * 40 + e]  = qv;
        Kk[pix * 40 + e] = kv;
        Vt[e * 72 + pix] = vv;
    }
    __syncthreads();

    // ---- fragments (must both be in regs before P overlays Q/K) ----
    s16x8 kf[4], qf[4];
    #pragma unroll
    for (int m = 0; m < 4; ++m)
        kf[m] = *(const s16x8*)&Kk[(m * 16 + l15) * 40 + l4 * 8];
    #pragma unroll
    for (int n = 0; n < 4; ++n)
        qf[n] = *(const s16x8*)&Q[(n * 16 + l15) * 40 + l4 * 8];

    f32x4 sc[4][4] = {};
    #pragma unroll
    for (int m = 0; m < 4; ++m)
        #pragma unroll
        for (int n = 0; n < 4; ++n)
            sc[m][n] = __builtin_amdgcn_mfma_f32_16x16x32_bf16(
                kf[m], qf[n], sc[m][n], 0, 0, 0);   // S^T: rows k, cols q

    // ---- softmax over k (rows of S^T) for each q-column ----
    const float scale = 0.17677669529663687f;       // 1/sqrt(32)
    const float* ev = emb4 + ((bh == 7 ? 1 : 0) + (bw == 7 ? 2 : 0)) * 4096;

    #pragma unroll
    for (int n = 0; n < 4; ++n) {
        const int q = n * 16 + l15;
        float vals[4][4];
        float mx = -INFINITY;
        #pragma unroll
        for (int m = 0; m < 4; ++m)
            #pragma unroll
            for (int r = 0; r < 4; ++r) {
                int k = m * 16 + l4 * 4 + r;
                float v = sc[m][n][r] * scale + ev[q * 64 + k];
                vals[m][r] = v;
                mx = fmaxf(mx, v);
            }
        mx = fmaxf(mx, __shfl_xor(mx, 16));
        mx = fmaxf(mx, __shfl_xor(mx, 32));
        float sum = 0.f;
        #pragma unroll
        for (int m = 0; m < 4; ++m)
            #pragma unroll
            for (int r = 0; r < 4; ++r) {
                float p = __expf(vals[m][r] - mx);
                vals[m][r] = p;
                sum += p;
            }
        sum += __shfl_xor(sum, 16);
        sum += __shfl_xor(sum, 32);
        float inv = 1.f / sum;
        #pragma unroll
        for (int m = 0; m < 4; ++m)
            #pragma unroll
            for (int r = 0; r < 4; ++r)
                P[q * 72 + m * 16 + l4 * 4 + r] = f2b(vals[m][r] * inv);
    }
    __syncthreads();

    // ---- PV: out[q][e] = sum_k P[q][k] V[k][e], K = 64 in 2 halves ----
    f32x4 o[4][2] = {};
    #pragma unroll
    for (int kh = 0; kh < 2; ++kh) {
        s16x8 pf[4], vf[2];
        #pragma unroll
        for (int mq = 0; mq < 4; ++mq)
            pf[mq] = *(const s16x8*)&P[(mq * 16 + l15) * 72 + kh * 32 + l4 * 8];
        #pragma unroll
        for (int ne = 0; ne < 2; ++ne)
            vf[ne] = *(const s16x8*)&Vt[(ne * 16 + l15) * 72 + kh * 32 + l4 * 8];
        #pragma unroll
        for (int mq = 0; mq < 4; ++mq)
            #pragma unroll
            for (int ne = 0; ne < 2; ++ne)
                o[mq][ne] = __builtin_amdgcn_mfma_f32_16x16x32_bf16(
                    pf[mq], vf[ne], o[mq][ne], 0, 0, 0);
    }

    // ---- store with roll(+3,+3) fused ----
    #pragma unroll
    for (int mq = 0; mq < 4; ++mq) {
        #pragma unroll
        for (int r = 0; r < 4; ++r) {
            int q = mq * 16 + l4 * 4 + r;
            if (q < 49) {
                int fr = (bh * 7 + q / 7 + 3) % IMG;
                int fc = (bw * 7 + q % 7 + 3) % IMG;
                size_t rowb = ((size_t)(b * IMG + fr) * IMG + fc) * DIM + head * 32;
                #pragma unroll
                for (int ne = 0; ne < 2; ++ne)
                    att[rowb + ne * 16 + l15] = f2b(o[mq][ne][r]);
            }
        }
    }
}

// ---------------------------------------------------------------------------
extern "C" void kernel_launch(void* const* d_in, const int* in_sizes, int n_in,
                              void* d_out, int out_size, void* d_ws, size_t ws_size,
                              hipStream_t stream) {
    const float* x     = (const float*)d_in[0];
    const float* w_qkv = (const float*)d_in[1];
    const float* b_qkv = (const float*)d_in[2];
    const float* w_out = (const float*)d_in[3];
    const float* b_out = (const float*)d_in[4];
    float* out = (float*)d_out;

    char* wsp = (char*)d_ws;
    float* emb4  = (float*)wsp;                                  // 64 KB
    u16*   wqkvt = (u16*)(wsp + 65536);                          // [1152][384]
    u16*   woutt = (u16*)(wsp + 65536 + 884736);                 // [384][384]
    const size_t fixed = 65536 + 884736 + 294912;                // 1,245,184 B

    const size_t perb = (size_t)ROWS_PER_B * (DIM + NQKV + DIM) * 2;
    int nb = 16;
    while (nb > 2 && fixed + (size_t)nb * perb > ws_size) nb >>= 1;

    u16* xb   = (u16*)(wsp + fixed);
    u16* qkvb = xb   + (size_t)nb * ROWS_PER_B * DIM;
    u16* attb = qkvb + (size_t)nb * ROWS_PER_B * NQKV;

    emb4_init_kernel<<<16, 256, 0, stream>>>(emb4);
    cvt_transpose_bf16<<<(384 * 1152 + 255) / 256, 256, 0, stream>>>(w_qkv, wqkvt, 384, 1152);
    cvt_transpose_bf16<<<(384 * 384 + 255) / 256, 256, 0, stream>>>(w_out, woutt, 384, 384);

    for (int b0 = 0; b0 < 16; b0 += nb) {
        const int rows = nb * ROWS_PER_B;
        const float* xa = x + (size_t)b0 * ROWS_PER_B * DIM;

        cvt_f32_bf16<<<(rows * DIM / 4 + 255) / 256, 256, 0, stream>>>(
            xa, xb, rows * DIM / 4);

        mfma_gemm<0><<<dim3(NQKV / 128, rows / 128), 256, 0, stream>>>(
            xb, wqkvt, b_qkv, qkvb, nullptr, NQKV, DIM);

        attn_mfma_kernel<<<nb * 192, 256, 0, stream>>>(qkvb, emb4, attb);

        mfma_gemm<1><<<dim3(DIM / 128, rows / 128), 256, 0, stream>>>(
            attb, woutt, b_out, nullptr, out + (size_t)b0 * ROWS_PER_B * DIM, DIM, DIM);
    }
}

// Round 7
// 201.633 us; speedup vs baseline: 1.8908x; 1.2338x over previous
//
#include <hip/hip_runtime.h>
#include <math.h>

// Problem constants
#define DIM   384
#define NQKV  1152
#define IMG   56
#define ROWS_PER_B (IMG*IMG)           // 3136 pixels per batch image

typedef unsigned short u16;
typedef unsigned int u32;
typedef __attribute__((ext_vector_type(4))) float f32x4;
typedef __attribute__((ext_vector_type(8))) short s16x8;

__device__ __forceinline__ u16 f2b(float f) {           // fp32 -> bf16 RNE
    unsigned u = __float_as_uint(f);
    return (u16)((u + 0x7fffu + ((u >> 16) & 1u)) >> 16);
}

// ---------------------------------------------------------------------------
// Kernel 1: masked relative-embedding table, 4 variants [4][64][64]:
//   v bit0: row-shift mask active (bh==7), bit1: col-shift mask (bw==7).
// Pad (q>=49 || k>=49) = -inf so padded K-rows softmax to zero.
// Sinusoid math bit-faithful to numpy arange fill (verified R3). DO NOT TOUCH.
// ---------------------------------------------------------------------------
__global__ __launch_bounds__(256) void emb4_init_kernel(float* __restrict__ emb4) {
    int idx = blockIdx.x * 256 + threadIdx.x;
    if (idx >= 64 * 64) return;
    int q = idx >> 6, k = idx & 63;

    bool pad = (q >= 49) || (k >= 49);
    float base = 0.f;
    if (!pad) {
        const double step  = 1.0 / 7.0;
        const double delta = __dsub_rn(__dadd_rn(1.0, step), 1.0);
        double xk = __dadd_rn(1.0, __dmul_rn((double)k, delta));
        double xq = __dadd_rn(1.0, __dmul_rn((double)q, delta));
        int xi = (int)__dsub_rn(xk, xq);
        int yi = (k % 7) - (q % 7);
        int r = xi % 13; if (r < 0) r += 13;
        int c = yi % 13; if (c < 0) c += 13;
        const float scl = (float)(-0.7084877209212449);  // -log(10000)/13
        if ((c & 1) == 0) base = sinf((float)r * expf((float)c * scl));
        else              base = cosf((float)r * expf((float)(c - 1) * scl));
    }
    bool rmask = !pad && ((q >= 28) != (k >= 28));
    bool cmask = !pad && ((q % 7 >= 4) != (k % 7 >= 4));
    #pragma unroll
    for (int v = 0; v < 4; ++v) {
        float val = base;
        if (pad || ((v & 1) && rmask) || ((v & 2) && cmask)) val = -INFINITY;
        emb4[v * 4096 + idx] = val;
    }
}

// ---------------------------------------------------------------------------
// Conversion kernels
// ---------------------------------------------------------------------------
__global__ __launch_bounds__(256) void cvt_f32_bf16(
    const float* __restrict__ in, u16* __restrict__ out, int n4) {
    int i = blockIdx.x * 256 + threadIdx.x;
    if (i >= n4) return;
    float4 v = ((const float4*)in)[i];
    ushort4 o;
    o.x = f2b(v.x); o.y = f2b(v.y); o.z = f2b(v.z); o.w = f2b(v.w);
    ((ushort4*)out)[i] = o;
}

// plain transpose: w [R][C] fp32 -> wt [C][R] bf16
__global__ __launch_bounds__(256) void cvt_transpose_bf16(
    const float* __restrict__ w, u16* __restrict__ wt, int R, int C) {
    int i = blockIdx.x * 256 + threadIdx.x;
    if (i >= R * C) return;
    int r = i / C, c = i % C;
    wt[(size_t)c * R + r] = f2b(w[i]);
}

// QKV transpose with de-interleaving row permutation:
// GEMM output column n' = comp*384 + ch  <=>  original column ch*3 + comp.
// So the GEMM directly writes [row][ Q(0..383) | K | V ] with per-head
// channels contiguous — de-interleave is free.
__global__ __launch_bounds__(256) void cvt_transpose_qkv(
    const float* __restrict__ w, u16* __restrict__ wt) {
    int i = blockIdx.x * 256 + threadIdx.x;
    if (i >= 384 * 1152) return;
    int k = i / 1152, col = i % 1152;
    int ch = col / 3, comp = col % 3;
    int np = comp * 384 + ch;
    wt[(size_t)np * 384 + k] = f2b(w[i]);
}

__global__ __launch_bounds__(256) void bias_perm_kernel(
    const float* __restrict__ b, float* __restrict__ bp) {
    int n = blockIdx.x * 256 + threadIdx.x;
    if (n >= 1152) return;
    int comp = n / 384, ch = n % 384;
    bp[n] = b[ch * 3 + comp];
}

// ---------------------------------------------------------------------------
// MFMA bf16 GEMM (verified R5): C[M][N] = A[M][K] @ Bt[N][K]^T + bias.
// ---------------------------------------------------------------------------
template <int MODE>
__global__ __launch_bounds__(256) void mfma_gemm(
    const u16* __restrict__ A, const u16* __restrict__ Bt,
    const float* __restrict__ bias,
    u16* __restrict__ outb, float* __restrict__ outf,
    int N, int K)
{
    __shared__ __align__(16) u16 As[128][40];
    __shared__ __align__(16) u16 Bs[128][40];

    const int tid  = threadIdx.x;
    const int lane = tid & 63;
    const int wid  = tid >> 6;
    const int wr   = wid >> 1, wc = wid & 1;
    const int l15  = lane & 15, l4 = lane >> 4;
    const int bm = blockIdx.y, bn = blockIdx.x;

    const int srow = tid >> 2;
    const int sk   = (tid & 3) * 8;

    const u16* Ap = A  + (size_t)(bm * 128 + srow) * K + sk;
    const u16* Bp = Bt + (size_t)(bn * 128 + srow) * K + sk;

    f32x4 acc[4][4] = {};

    for (int kt = 0; kt < K; kt += 32) {
        s16x8 a0 = *(const s16x8*)(Ap + kt);
        s16x8 a1 = *(const s16x8*)(Ap + (size_t)64 * K + kt);
        s16x8 b0 = *(const s16x8*)(Bp + kt);
        s16x8 b1 = *(const s16x8*)(Bp + (size_t)64 * K + kt);
        __syncthreads();
        *(s16x8*)&As[srow][sk]      = a0;
        *(s16x8*)&As[srow + 64][sk] = a1;
        *(s16x8*)&Bs[srow][sk]      = b0;
        *(s16x8*)&Bs[srow + 64][sk] = b1;
        __syncthreads();

        s16x8 af[4], bf[4];
        #pragma unroll
        for (int m = 0; m < 4; ++m)
            af[m] = *(const s16x8*)&As[wr * 64 + m * 16 + l15][l4 * 8];
        #pragma unroll
        for (int n = 0; n < 4; ++n)
            bf[n] = *(const s16x8*)&Bs[wc * 64 + n * 16 + l15][l4 * 8];
        #pragma unroll
        for (int m = 0; m < 4; ++m)
            #pragma unroll
            for (int n = 0; n < 4; ++n)
                acc[m][n] = __builtin_amdgcn_mfma_f32_16x16x32_bf16(
                    af[m], bf[n], acc[m][n], 0, 0, 0);
    }

    const int grow0 = bm * 128 + wr * 64;
    const int gcol0 = bn * 128 + wc * 64;
    #pragma unroll
    for (int m = 0; m < 4; ++m) {
        #pragma unroll
        for (int n = 0; n < 4; ++n) {
            int col = gcol0 + n * 16 + l15;
            float bz = bias[col];
            #pragma unroll
            for (int r = 0; r < 4; ++r) {
                int row = grow0 + m * 16 + l4 * 4 + r;
                float v = acc[m][n][r] + bz;
                if constexpr (MODE == 0)
                    outb[(size_t)row * N + col] = f2b(v);
                else
                    outf[(size_t)row * N + col] = v;
            }
        }
    }
}

// ---------------------------------------------------------------------------
// Kernel 3: MFMA windowed attention, stageless.
// Block = 4 waves = 4 heads of one (b, wh, ww) window; 3 blocks/window.
// qkv: bf16 [row][1152] de-interleaved: Q@0, K@384, V@768; head ch contiguous.
// Q/K MFMA fragments load DIRECTLY from global (row = one pixel, 8 contiguous
// ch). V B-fragment via scalar loads. Only P round-trips LDS (per-wave
// private arena -> no barriers after the LUT one). Rows/cols >=49 carry real
// wrapped-pixel data; emb4 -inf pad masks them through softmax.
// ---------------------------------------------------------------------------
__global__ __launch_bounds__(256) void attn_mfma_kernel(
    const u16* __restrict__ qkv, const float* __restrict__ emb4,
    u16* __restrict__ att)
{
    __shared__ __align__(16) u16 P4[4][64 * 72];   // 36864 B
    __shared__ int rowIn[64];
    __shared__ int rowOut[64];

    const int tid  = threadIdx.x;
    const int lane = tid & 63;
    const int wid  = tid >> 6;
    const int l15  = lane & 15, l4 = lane >> 4;

    const int blk = blockIdx.x;
    const int hg  = blk % 3;
    const int win = (blk / 3) & 63;
    const int b   = blk / 192;
    const int bw  = win & 7, bh = win >> 3;
    const int head = hg * 4 + wid;

    if (tid < 64) {                                 // roll(-4,-4) gather LUT
        int pix = tid;
        int gr = (bh * 7 + pix / 7 + 4) % IMG;
        int gc = (bw * 7 + pix % 7 + 4) % IMG;
        rowIn[pix] = (b * IMG + gr) * IMG + gc;
    } else if (tid < 128) {                         // roll(+3,+3) scatter LUT
        int q = tid - 64;
        int fr = (bh * 7 + q / 7 + 3) % IMG;
        int fc = (bw * 7 + q % 7 + 3) % IMG;
        rowOut[q] = (b * IMG + fr) * IMG + fc;
    }
    __syncthreads();

    // ---- Q/K fragments straight from global ----
    s16x8 qf[4], kf[4];
    #pragma unroll
    for (int n = 0; n < 4; ++n) {
        int pix = n * 16 + l15;
        size_t base = (size_t)rowIn[pix] * NQKV + head * 32 + l4 * 8;
        qf[n] = *(const s16x8*)(qkv + base);          // Q
        kf[n] = *(const s16x8*)(qkv + base + 384);    // K
    }

    // ---- S^T = mfma(K, Q): rows k, cols q ----
    f32x4 sc[4][4] = {};
    #pragma unroll
    for (int m = 0; m < 4; ++m)
        #pragma unroll
        for (int n = 0; n < 4; ++n)
            sc[m][n] = __builtin_amdgcn_mfma_f32_16x16x32_bf16(
                kf[m], qf[n], sc[m][n], 0, 0, 0);

    // ---- softmax over k for each q-column, P -> private LDS ----
    const float scale = 0.17677669529663687f;        // 1/sqrt(32)
    const float* ev = emb4 + ((bh == 7 ? 1 : 0) + (bw == 7 ? 2 : 0)) * 4096;
    u16* P = P4[wid];
    u32* P32 = (u32*)P;

    #pragma unroll
    for (int n = 0; n < 4; ++n) {
        const int q = n * 16 + l15;
        float vals[4][4];
        float mx = -INFINITY;
        #pragma unroll
        for (int m = 0; m < 4; ++m) {
            float4 e4 = *(const float4*)(ev + q * 64 + m * 16 + l4 * 4);
            #pragma unroll
            for (int r = 0; r < 4; ++r) {
                float v = sc[m][n][r] * scale + ((const float*)&e4)[r];
                vals[m][r] = v;
                mx = fmaxf(mx, v);
            }
        }
        mx = fmaxf(mx, __shfl_xor(mx, 16));
        mx = fmaxf(mx, __shfl_xor(mx, 32));
        float sum = 0.f;
        #pragma unroll
        for (int m = 0; m < 4; ++m)
            #pragma unroll
            for (int r = 0; r < 4; ++r) {
                float p = __expf(vals[m][r] - mx);
                vals[m][r] = p;
                sum += p;
            }
        sum += __shfl_xor(sum, 16);
        sum += __shfl_xor(sum, 32);
        float inv = 1.f / sum;
        #pragma unroll
        for (int m = 0; m < 4; ++m) {
            u32 w0 = (u32)f2b(vals[m][0] * inv) | ((u32)f2b(vals[m][1] * inv) << 16);
            u32 w1 = (u32)f2b(vals[m][2] * inv) | ((u32)f2b(vals[m][3] * inv) << 16);
            int bidx = q * 36 + m * 8 + l4 * 2;      // u32 index: (q*72+m*16+l4*4)/2
            P32[bidx]     = w0;
            P32[bidx + 1] = w1;
        }
    }
    // per-wave private LDS RAW: compiler inserts lgkmcnt waits; no barrier.

    // ---- PV: o[q][e] = sum_k P[q][k] V[k][e] ----
    f32x4 o[4][2] = {};
    #pragma unroll
    for (int kh = 0; kh < 2; ++kh) {
        s16x8 pf[4];
        #pragma unroll
        for (int mq = 0; mq < 4; ++mq)
            pf[mq] = *(const s16x8*)&P[(mq * 16 + l15) * 72 + kh * 32 + l4 * 8];
        s16x8 vf[2];
        #pragma unroll
        for (int ne = 0; ne < 2; ++ne) {
            #pragma unroll
            for (int j = 0; j < 8; ++j) {
                int pix = kh * 32 + l4 * 8 + j;
                vf[ne][j] = (short)qkv[(size_t)rowIn[pix] * NQKV + 768
                                       + head * 32 + ne * 16 + l15];
            }
        }
        #pragma unroll
        for (int mq = 0; mq < 4; ++mq)
            #pragma unroll
            for (int ne = 0; ne < 2; ++ne)
                o[mq][ne] = __builtin_amdgcn_mfma_f32_16x16x32_bf16(
                    pf[mq], vf[ne], o[mq][ne], 0, 0, 0);
    }

    // ---- store with roll(+3,+3) fused ----
    #pragma unroll
    for (int mq = 0; mq < 4; ++mq) {
        #pragma unroll
        for (int r = 0; r < 4; ++r) {
            int q = mq * 16 + l4 * 4 + r;
            if (q < 49) {
                size_t rowb = (size_t)rowOut[q] * DIM + head * 32;
                #pragma unroll
                for (int ne = 0; ne < 2; ++ne)
                    att[rowb + ne * 16 + l15] = f2b(o[mq][ne][r]);
            }
        }
    }
}

// ---------------------------------------------------------------------------
extern "C" void kernel_launch(void* const* d_in, const int* in_sizes, int n_in,
                              void* d_out, int out_size, void* d_ws, size_t ws_size,
                              hipStream_t stream) {
    const float* x     = (const float*)d_in[0];
    const float* w_qkv = (const float*)d_in[1];
    const float* b_qkv = (const float*)d_in[2];
    const float* w_out = (const float*)d_in[3];
    const float* b_out = (const float*)d_in[4];
    float* out = (float*)d_out;

    char* wsp = (char*)d_ws;
    float* emb4  = (float*)wsp;                                  // 64 KB
    u16*   wqkvt = (u16*)(wsp + 65536);                          // [1152][384]
    u16*   woutt = (u16*)(wsp + 65536 + 884736);                 // [384][384]
    float* bqkvp = (float*)(wsp + 65536 + 884736 + 294912);      // [1152]
    const size_t fixed = 65536 + 884736 + 294912 + 4608;         // 1,249,792 B

    const size_t perb = (size_t)ROWS_PER_B * (DIM + NQKV + DIM) * 2;
    int nb = 16;
    while (nb > 2 && fixed + (size_t)nb * perb > ws_size) nb >>= 1;

    u16* xb   = (u16*)(wsp + fixed);
    u16* qkvb = xb   + (size_t)nb * ROWS_PER_B * DIM;
    u16* attb = qkvb + (size_t)nb * ROWS_PER_B * NQKV;

    emb4_init_kernel<<<16, 256, 0, stream>>>(emb4);
    cvt_transpose_qkv<<<(384 * 1152 + 255) / 256, 256, 0, stream>>>(w_qkv, wqkvt);
    cvt_transpose_bf16<<<(384 * 384 + 255) / 256, 256, 0, stream>>>(w_out, woutt, 384, 384);
    bias_perm_kernel<<<5, 256, 0, stream>>>(b_qkv, bqkvp);

    for (int b0 = 0; b0 < 16; b0 += nb) {
        const int rows = nb * ROWS_PER_B;
        const float* xa = x + (size_t)b0 * ROWS_PER_B * DIM;

        cvt_f32_bf16<<<(rows * DIM / 4 + 255) / 256, 256, 0, stream>>>(
            xa, xb, rows * DIM / 4);

        mfma_gemm<0><<<dim3(NQKV / 128, rows / 128), 256, 0, stream>>>(
            xb, wqkvt, bqkvp, qkvb, nullptr, NQKV, DIM);

        attn_mfma_kernel<<<nb * 192, 256, 0, stream>>>(qkvb, emb4, attb);

        mfma_gemm<1><<<dim3(DIM / 128, rows / 128), 256, 0, stream>>>(
            attb, woutt, b_out, nullptr, out + (size_t)b0 * ROWS_PER_B * DIM, DIM, DIM);
    }
}

// Round 8
// 184.670 us; speedup vs baseline: 2.0644x; 1.0919x over previous
//
#include <hip/hip_runtime.h>
#include <math.h>

// Problem constants
#define DIM   384
#define NQKV  1152
#define IMG   56
#define ROWS_PER_B (IMG*IMG)           // 3136 pixels per batch image

typedef unsigned short u16;
typedef unsigned int u32;
typedef __attribute__((ext_vector_type(4))) float f32x4;
typedef __attribute__((ext_vector_type(8))) short s16x8;

__device__ __forceinline__ u16 f2b(float f) {           // fp32 -> bf16 RNE
    unsigned u = __float_as_uint(f);
    return (u16)((u + 0x7fffu + ((u >> 16) & 1u)) >> 16);
}

// async global->LDS, 16B/lane, dest = wave-uniform base + lane*16
__device__ __forceinline__ void gl2lds16(const u16* g, u16* l) {
    __builtin_amdgcn_global_load_lds(
        (const __attribute__((address_space(1))) void*)g,
        (__attribute__((address_space(3))) void*)l, 16, 0, 0);
}

// ---------------------------------------------------------------------------
// Kernel 1: masked relative-embedding table, 4 variants [4][64][64].
// Sinusoid math bit-faithful to numpy arange fill (verified R3). DO NOT TOUCH.
// ---------------------------------------------------------------------------
__global__ __launch_bounds__(256) void emb4_init_kernel(float* __restrict__ emb4) {
    int idx = blockIdx.x * 256 + threadIdx.x;
    if (idx >= 64 * 64) return;
    int q = idx >> 6, k = idx & 63;

    bool pad = (q >= 49) || (k >= 49);
    float base = 0.f;
    if (!pad) {
        const double step  = 1.0 / 7.0;
        const double delta = __dsub_rn(__dadd_rn(1.0, step), 1.0);
        double xk = __dadd_rn(1.0, __dmul_rn((double)k, delta));
        double xq = __dadd_rn(1.0, __dmul_rn((double)q, delta));
        int xi = (int)__dsub_rn(xk, xq);
        int yi = (k % 7) - (q % 7);
        int r = xi % 13; if (r < 0) r += 13;
        int c = yi % 13; if (c < 0) c += 13;
        const float scl = (float)(-0.7084877209212449);  // -log(10000)/13
        if ((c & 1) == 0) base = sinf((float)r * expf((float)c * scl));
        else              base = cosf((float)r * expf((float)(c - 1) * scl));
    }
    bool rmask = !pad && ((q >= 28) != (k >= 28));
    bool cmask = !pad && ((q % 7 >= 4) != (k % 7 >= 4));
    #pragma unroll
    for (int v = 0; v < 4; ++v) {
        float val = base;
        if (pad || ((v & 1) && rmask) || ((v & 2) && cmask)) val = -INFINITY;
        emb4[v * 4096 + idx] = val;
    }
}

// ---------------------------------------------------------------------------
// Conversion kernels
// ---------------------------------------------------------------------------
__global__ __launch_bounds__(256) void cvt_f32_bf16(
    const float* __restrict__ in, u16* __restrict__ out, int n4) {
    int i = blockIdx.x * 256 + threadIdx.x;
    if (i >= n4) return;
    float4 v = ((const float4*)in)[i];
    ushort4 o;
    o.x = f2b(v.x); o.y = f2b(v.y); o.z = f2b(v.z); o.w = f2b(v.w);
    ((ushort4*)out)[i] = o;
}

__global__ __launch_bounds__(256) void cvt_transpose_bf16(
    const float* __restrict__ w, u16* __restrict__ wt, int R, int C) {
    int i = blockIdx.x * 256 + threadIdx.x;
    if (i >= R * C) return;
    int r = i / C, c = i % C;
    wt[(size_t)c * R + r] = f2b(w[i]);
}

// QKV transpose with de-interleaving row permutation: GEMM col n' = comp*384+ch
__global__ __launch_bounds__(256) void cvt_transpose_qkv(
    const float* __restrict__ w, u16* __restrict__ wt) {
    int i = blockIdx.x * 256 + threadIdx.x;
    if (i >= 384 * 1152) return;
    int k = i / 1152, col = i % 1152;
    int ch = col / 3, comp = col % 3;
    int np = comp * 384 + ch;
    wt[(size_t)np * 384 + k] = f2b(w[i]);
}

__global__ __launch_bounds__(256) void bias_perm_kernel(
    const float* __restrict__ b, float* __restrict__ bp) {
    int n = blockIdx.x * 256 + threadIdx.x;
    if (n >= 1152) return;
    int comp = n / 384, ch = n % 384;
    bp[n] = b[ch * 3 + comp];
}

// ---------------------------------------------------------------------------
// MFMA bf16 GEMM: C[M][N] = A[M][K] @ Bt[N][K]^T + bias.
// 128x128 tile, BK=32, 4 waves (64x64 quadrants, 4x4 frags of 16x16x32).
// Staging: global_load_lds width=16 into LINEAR [128][32] bf16 tiles (8 KB
// each). Rule-21 both-sides swizzle: phys slot16 = log slot16 ^ ((row>>1)&3)
// (XOR bits[5:4] with bits[8:7], involution). Inverse swizzle folded into the
// per-lane GLOBAL source address; ds_read_b128 applies the same XOR -> 16
// lanes spread over 8 16B-slots covering all 32 banks = 2-way (free, m136).
// Grid: bijective XCD swizzle (m204) so each XCD owns a contiguous bm range.
// ---------------------------------------------------------------------------
template <int MODE>
__global__ __launch_bounds__(256) void mfma_gemm(
    const u16* __restrict__ A, const u16* __restrict__ Bt,
    const float* __restrict__ bias,
    u16* __restrict__ outb, float* __restrict__ outf,
    int N, int K)
{
    __shared__ __align__(16) u16 As[4096];   // [128][32] swizzled
    __shared__ __align__(16) u16 Bs[4096];

    const int tid  = threadIdx.x;
    const int lane = tid & 63;
    const int wid  = tid >> 6;
    const int wr   = wid >> 1, wc = wid & 1;
    const int l15  = lane & 15, l4 = lane >> 4;

    // bijective XCD remap (m204): contiguous chunk of blocks per XCD
    const int gx  = gridDim.x;
    const int nwg = gx * gridDim.y;
    int wg  = blockIdx.y * gx + blockIdx.x;
    int q8  = nwg >> 3, r8 = nwg & 7;
    int xcd = wg & 7, idx = wg >> 3;
    int nid = (xcd < r8 ? xcd * (q8 + 1) : r8 * (q8 + 1) + (xcd - r8) * q8) + idx;
    const int bm = nid / gx, bn = nid % gx;

    // staging geometry: issue i covers rows i*64 + wid*16 + (lane>>2),
    // phys slot16 = lane&3; logical slot = (lane&3) ^ ((srow>>1)&3)
    const int srow  = lane >> 2;
    const int sslot = (lane & 3) ^ ((srow >> 1) & 3);

    const u16* pA0 = A  + (size_t)(bm * 128 +      wid * 16 + srow) * K + sslot * 8;
    const u16* pA1 = A  + (size_t)(bm * 128 + 64 + wid * 16 + srow) * K + sslot * 8;
    const u16* pB0 = Bt + (size_t)(bn * 128 +      wid * 16 + srow) * K + sslot * 8;
    const u16* pB1 = Bt + (size_t)(bn * 128 + 64 + wid * 16 + srow) * K + sslot * 8;
    u16* lA0 = (u16*)((char*)As + wid * 1024);
    u16* lA1 = (u16*)((char*)As + 4096 + wid * 1024);
    u16* lB0 = (u16*)((char*)Bs + wid * 1024);
    u16* lB1 = (u16*)((char*)Bs + 4096 + wid * 1024);

    f32x4 acc[4][4] = {};

    for (int kt = 0; kt < K; kt += 32) {
        __syncthreads();                     // prev-iter ds_reads done
        gl2lds16(pA0 + kt, lA0);
        gl2lds16(pA1 + kt, lA1);
        gl2lds16(pB0 + kt, lB0);
        gl2lds16(pB1 + kt, lB1);
        __syncthreads();                     // drains vmcnt(0); data visible

        s16x8 af[4], bf[4];
        #pragma unroll
        for (int m = 0; m < 4; ++m) {
            int rm = wr * 64 + m * 16 + l15;
            af[m] = *(const s16x8*)((const char*)As + rm * 64
                                    + ((l4 ^ ((rm >> 1) & 3)) << 4));
        }
        #pragma unroll
        for (int n = 0; n < 4; ++n) {
            int rn = wc * 64 + n * 16 + l15;
            bf[n] = *(const s16x8*)((const char*)Bs + rn * 64
                                    + ((l4 ^ ((rn >> 1) & 3)) << 4));
        }
        #pragma unroll
        for (int m = 0; m < 4; ++m)
            #pragma unroll
            for (int n = 0; n < 4; ++n)
                acc[m][n] = __builtin_amdgcn_mfma_f32_16x16x32_bf16(
                    af[m], bf[n], acc[m][n], 0, 0, 0);
    }

    const int grow0 = bm * 128 + wr * 64;
    const int gcol0 = bn * 128 + wc * 64;
    #pragma unroll
    for (int m = 0; m < 4; ++m) {
        #pragma unroll
        for (int n = 0; n < 4; ++n) {
            int col = gcol0 + n * 16 + l15;
            float bz = bias[col];
            #pragma unroll
            for (int r = 0; r < 4; ++r) {
                int row = grow0 + m * 16 + l4 * 4 + r;
                float v = acc[m][n][r] + bz;
                if constexpr (MODE == 0)
                    outb[(size_t)row * N + col] = f2b(v);
                else
                    outf[(size_t)row * N + col] = v;
            }
        }
    }
}

// ---------------------------------------------------------------------------
// Kernel 3: MFMA windowed attention, stageless (verified R7). Unchanged.
// ---------------------------------------------------------------------------
__global__ __launch_bounds__(256) void attn_mfma_kernel(
    const u16* __restrict__ qkv, const float* __restrict__ emb4,
    u16* __restrict__ att)
{
    __shared__ __align__(16) u16 P4[4][64 * 72];   // 36864 B
    __shared__ int rowIn[64];
    __shared__ int rowOut[64];

    const int tid  = threadIdx.x;
    const int lane = tid & 63;
    const int wid  = tid >> 6;
    const int l15  = lane & 15, l4 = lane >> 4;

    const int blk = blockIdx.x;
    const int hg  = blk % 3;
    const int win = (blk / 3) & 63;
    const int b   = blk / 192;
    const int bw  = win & 7, bh = win >> 3;
    const int head = hg * 4 + wid;

    if (tid < 64) {                                 // roll(-4,-4) gather LUT
        int pix = tid;
        int gr = (bh * 7 + pix / 7 + 4) % IMG;
        int gc = (bw * 7 + pix % 7 + 4) % IMG;
        rowIn[pix] = (b * IMG + gr) * IMG + gc;
    } else if (tid < 128) {                         // roll(+3,+3) scatter LUT
        int q = tid - 64;
        int fr = (bh * 7 + q / 7 + 3) % IMG;
        int fc = (bw * 7 + q % 7 + 3) % IMG;
        rowOut[q] = (b * IMG + fr) * IMG + fc;
    }
    __syncthreads();

    s16x8 qf[4], kf[4];
    #pragma unroll
    for (int n = 0; n < 4; ++n) {
        int pix = n * 16 + l15;
        size_t base = (size_t)rowIn[pix] * NQKV + head * 32 + l4 * 8;
        qf[n] = *(const s16x8*)(qkv + base);          // Q
        kf[n] = *(const s16x8*)(qkv + base + 384);    // K
    }

    f32x4 sc[4][4] = {};
    #pragma unroll
    for (int m = 0; m < 4; ++m)
        #pragma unroll
        for (int n = 0; n < 4; ++n)
            sc[m][n] = __builtin_amdgcn_mfma_f32_16x16x32_bf16(
                kf[m], qf[n], sc[m][n], 0, 0, 0);

    const float scale = 0.17677669529663687f;        // 1/sqrt(32)
    const float* ev = emb4 + ((bh == 7 ? 1 : 0) + (bw == 7 ? 2 : 0)) * 4096;
    u16* P = P4[wid];
    u32* P32 = (u32*)P;

    #pragma unroll
    for (int n = 0; n < 4; ++n) {
        const int q = n * 16 + l15;
        float vals[4][4];
        float mx = -INFINITY;
        #pragma unroll
        for (int m = 0; m < 4; ++m) {
            float4 e4 = *(const float4*)(ev + q * 64 + m * 16 + l4 * 4);
            #pragma unroll
            for (int r = 0; r < 4; ++r) {
                float v = sc[m][n][r] * scale + ((const float*)&e4)[r];
                vals[m][r] = v;
                mx = fmaxf(mx, v);
            }
        }
        mx = fmaxf(mx, __shfl_xor(mx, 16));
        mx = fmaxf(mx, __shfl_xor(mx, 32));
        float sum = 0.f;
        #pragma unroll
        for (int m = 0; m < 4; ++m)
            #pragma unroll
            for (int r = 0; r < 4; ++r) {
                float p = __expf(vals[m][r] - mx);
                vals[m][r] = p;
                sum += p;
            }
        sum += __shfl_xor(sum, 16);
        sum += __shfl_xor(sum, 32);
        float inv = 1.f / sum;
        #pragma unroll
        for (int m = 0; m < 4; ++m) {
            u32 w0 = (u32)f2b(vals[m][0] * inv) | ((u32)f2b(vals[m][1] * inv) << 16);
            u32 w1 = (u32)f2b(vals[m][2] * inv) | ((u32)f2b(vals[m][3] * inv) << 16);
            int bidx = q * 36 + m * 8 + l4 * 2;
            P32[bidx]     = w0;
            P32[bidx + 1] = w1;
        }
    }
    // per-wave private LDS RAW: compiler inserts lgkmcnt waits; no barrier.

    f32x4 o[4][2] = {};
    #pragma unroll
    for (int kh = 0; kh < 2; ++kh) {
        s16x8 pf[4];
        #pragma unroll
        for (int mq = 0; mq < 4; ++mq)
            pf[mq] = *(const s16x8*)&P[(mq * 16 + l15) * 72 + kh * 32 + l4 * 8];
        s16x8 vf[2];
        #pragma unroll
        for (int ne = 0; ne < 2; ++ne) {
            #pragma unroll
            for (int j = 0; j < 8; ++j) {
                int pix = kh * 32 + l4 * 8 + j;
                vf[ne][j] = (short)qkv[(size_t)rowIn[pix] * NQKV + 768
                                       + head * 32 + ne * 16 + l15];
            }
        }
        #pragma unroll
        for (int mq = 0; mq < 4; ++mq)
            #pragma unroll
            for (int ne = 0; ne < 2; ++ne)
                o[mq][ne] = __builtin_amdgcn_mfma_f32_16x16x32_bf16(
                    pf[mq], vf[ne], o[mq][ne], 0, 0, 0);
    }

    #pragma unroll
    for (int mq = 0; mq < 4; ++mq) {
        #pragma unroll
        for (int r = 0; r < 4; ++r) {
            int q = mq * 16 + l4 * 4 + r;
            if (q < 49) {
                size_t rowb = (size_t)rowOut[q] * DIM + head * 32;
                #pragma unroll
                for (int ne = 0; ne < 2; ++ne)
                    att[rowb + ne * 16 + l15] = f2b(o[mq][ne][r]);
            }
        }
    }
}

// ---------------------------------------------------------------------------
extern "C" void kernel_launch(void* const* d_in, const int* in_sizes, int n_in,
                              void* d_out, int out_size, void* d_ws, size_t ws_size,
                              hipStream_t stream) {
    const float* x     = (const float*)d_in[0];
    const float* w_qkv = (const float*)d_in[1];
    const float* b_qkv = (const float*)d_in[2];
    const float* w_out = (const float*)d_in[3];
    const float* b_out = (const float*)d_in[4];
    float* out = (float*)d_out;

    char* wsp = (char*)d_ws;
    float* emb4  = (float*)wsp;                                  // 64 KB
    u16*   wqkvt = (u16*)(wsp + 65536);                          // [1152][384]
    u16*   woutt = (u16*)(wsp + 65536 + 884736);                 // [384][384]
    float* bqkvp = (float*)(wsp + 65536 + 884736 + 294912);      // [1152]
    const size_t fixed = 65536 + 884736 + 294912 + 4608;         // 1,249,792 B

    const size_t perb = (size_t)ROWS_PER_B * (DIM + NQKV + DIM) * 2;
    int nb = 16;
    while (nb > 2 && fixed + (size_t)nb * perb > ws_size) nb >>= 1;

    u16* xb   = (u16*)(wsp + fixed);
    u16* qkvb = xb   + (size_t)nb * ROWS_PER_B * DIM;
    u16* attb = qkvb + (size_t)nb * ROWS_PER_B * NQKV;

    emb4_init_kernel<<<16, 256, 0, stream>>>(emb4);
    cvt_transpose_qkv<<<(384 * 1152 + 255) / 256, 256, 0, stream>>>(w_qkv, wqkvt);
    cvt_transpose_bf16<<<(384 * 384 + 255) / 256, 256, 0, stream>>>(w_out, woutt, 384, 384);
    bias_perm_kernel<<<5, 256, 0, stream>>>(b_qkv, bqkvp);

    for (int b0 = 0; b0 < 16; b0 += nb) {
        const int rows = nb * ROWS_PER_B;
        const float* xa = x + (size_t)b0 * ROWS_PER_B * DIM;

        cvt_f32_bf16<<<(rows * DIM / 4 + 255) / 256, 256, 0, stream>>>(
            xa, xb, rows * DIM / 4);

        mfma_gemm<0><<<dim3(NQKV / 128, rows / 128), 256, 0, stream>>>(
            xb, wqkvt, bqkvp, qkvb, nullptr, NQKV, DIM);

        attn_mfma_kernel<<<nb * 192, 256, 0, stream>>>(qkvb, emb4, attb);

        mfma_gemm<1><<<dim3(DIM / 128, rows / 128), 256, 0, stream>>>(
            attb, woutt, b_out, nullptr, out + (size_t)b0 * ROWS_PER_B * DIM, DIM, DIM);
    }
}

// Round 9
// 182.013 us; speedup vs baseline: 2.0946x; 1.0146x over previous
//
#include <hip/hip_runtime.h>
#include <math.h>

// Problem constants
#define DIM   384
#define NQKV  1152
#define IMG   56
#define ROWS_PER_B (IMG*IMG)           // 3136 pixels per batch image

typedef unsigned short u16;
typedef unsigned int u32;
typedef __attribute__((ext_vector_type(4))) float f32x4;
typedef __attribute__((ext_vector_type(8))) short s16x8;

__device__ __forceinline__ u16 f2b(float f) {           // fp32 -> bf16 RNE
    unsigned u = __float_as_uint(f);
    return (u16)((u + 0x7fffu + ((u >> 16) & 1u)) >> 16);
}

// async global->LDS, 16B/lane, dest = wave-uniform base + lane*16
__device__ __forceinline__ void gl2lds16(const u16* g, u16* l) {
    __builtin_amdgcn_global_load_lds(
        (const __attribute__((address_space(1))) void*)g,
        (__attribute__((address_space(3))) void*)l, 16, 0, 0);
}

// ---------------------------------------------------------------------------
// Kernel 1: masked relative-embedding table, 4 variants [4][64][64].
// Sinusoid math bit-faithful to numpy arange fill (verified R3). DO NOT TOUCH.
// ---------------------------------------------------------------------------
__global__ __launch_bounds__(256) void emb4_init_kernel(float* __restrict__ emb4) {
    int idx = blockIdx.x * 256 + threadIdx.x;
    if (idx >= 64 * 64) return;
    int q = idx >> 6, k = idx & 63;

    bool pad = (q >= 49) || (k >= 49);
    float base = 0.f;
    if (!pad) {
        const double step  = 1.0 / 7.0;
        const double delta = __dsub_rn(__dadd_rn(1.0, step), 1.0);
        double xk = __dadd_rn(1.0, __dmul_rn((double)k, delta));
        double xq = __dadd_rn(1.0, __dmul_rn((double)q, delta));
        int xi = (int)__dsub_rn(xk, xq);
        int yi = (k % 7) - (q % 7);
        int r = xi % 13; if (r < 0) r += 13;
        int c = yi % 13; if (c < 0) c += 13;
        const float scl = (float)(-0.7084877209212449);  // -log(10000)/13
        if ((c & 1) == 0) base = sinf((float)r * expf((float)c * scl));
        else              base = cosf((float)r * expf((float)(c - 1) * scl));
    }
    bool rmask = !pad && ((q >= 28) != (k >= 28));
    bool cmask = !pad && ((q % 7 >= 4) != (k % 7 >= 4));
    #pragma unroll
    for (int v = 0; v < 4; ++v) {
        float val = base;
        if (pad || ((v & 1) && rmask) || ((v & 2) && cmask)) val = -INFINITY;
        emb4[v * 4096 + idx] = val;
    }
}

// ---------------------------------------------------------------------------
// Conversion kernels
// ---------------------------------------------------------------------------
__global__ __launch_bounds__(256) void cvt_f32_bf16(
    const float* __restrict__ in, u16* __restrict__ out, int n4) {
    int i = blockIdx.x * 256 + threadIdx.x;
    if (i >= n4) return;
    float4 v = ((const float4*)in)[i];
    ushort4 o;
    o.x = f2b(v.x); o.y = f2b(v.y); o.z = f2b(v.z); o.w = f2b(v.w);
    ((ushort4*)out)[i] = o;
}

__global__ __launch_bounds__(256) void cvt_transpose_bf16(
    const float* __restrict__ w, u16* __restrict__ wt, int R, int C) {
    int i = blockIdx.x * 256 + threadIdx.x;
    if (i >= R * C) return;
    int r = i / C, c = i % C;
    wt[(size_t)c * R + r] = f2b(w[i]);
}

// QKV transpose with de-interleaving row permutation: GEMM col n' = comp*384+ch
__global__ __launch_bounds__(256) void cvt_transpose_qkv(
    const float* __restrict__ w, u16* __restrict__ wt) {
    int i = blockIdx.x * 256 + threadIdx.x;
    if (i >= 384 * 1152) return;
    int k = i / 1152, col = i % 1152;
    int ch = col / 3, comp = col % 3;
    int np = comp * 384 + ch;
    wt[(size_t)np * 384 + k] = f2b(w[i]);
}

__global__ __launch_bounds__(256) void bias_perm_kernel(
    const float* __restrict__ b, float* __restrict__ bp) {
    int n = blockIdx.x * 256 + threadIdx.x;
    if (n >= 1152) return;
    int comp = n / 384, ch = n % 384;
    bp[n] = b[ch * 3 + comp];
}

// ---------------------------------------------------------------------------
// MFMA bf16 GEMM: C[M][N] = A[M][K] @ Bt[N][K]^T + bias.
// 128x128 tile, BK=32, 4 waves (64x64 quadrants, 4x4 frags of 16x16x32).
// Staging: global_load_lds width=16, rule-21 both-sides swizzle (R8-verified:
// bank conflicts = 0). NEW (T3/T4): ping-pong LDS dbuf with COUNTED vmcnt —
// per K-step: issue STAGE(t+1)->buf^1, s_waitcnt vmcnt(4) (t's loads done,
// t+1's stay in flight ACROSS the barrier), raw s_barrier, ds_read+MFMA(buf),
// then lgkmcnt(0)+s_barrier (reads complete before buf overwritten next iter).
// No vmcnt(0) drain in the main loop.
// Grid: bijective XCD swizzle (m204), R8-verified (FETCH 167->32 MB).
// ---------------------------------------------------------------------------
template <int MODE>
__global__ __launch_bounds__(256) void mfma_gemm(
    const u16* __restrict__ A, const u16* __restrict__ Bt,
    const float* __restrict__ bias,
    u16* __restrict__ outb, float* __restrict__ outf,
    int N, int K)
{
    __shared__ __align__(16) u16 As[2][4096];   // [128][32] swizzled, x2 dbuf
    __shared__ __align__(16) u16 Bs[2][4096];

    const int tid  = threadIdx.x;
    const int lane = tid & 63;
    const int wid  = tid >> 6;
    const int wr   = wid >> 1, wc = wid & 1;
    const int l15  = lane & 15, l4 = lane >> 4;

    // bijective XCD remap (m204): contiguous chunk of blocks per XCD
    const int gx  = gridDim.x;
    const int nwg = gx * gridDim.y;
    int wg  = blockIdx.y * gx + blockIdx.x;
    int q8  = nwg >> 3, r8 = nwg & 7;
    int xcd = wg & 7, idx = wg >> 3;
    int nid = (xcd < r8 ? xcd * (q8 + 1) : r8 * (q8 + 1) + (xcd - r8) * q8) + idx;
    const int bm = nid / gx, bn = nid % gx;

    // staging geometry: phys slot16 = lane&3; logical slot = (lane&3)^((srow>>1)&3)
    const int srow  = lane >> 2;
    const int sslot = (lane & 3) ^ ((srow >> 1) & 3);

    const u16* pA0 = A  + (size_t)(bm * 128 +      wid * 16 + srow) * K + sslot * 8;
    const u16* pA1 = A  + (size_t)(bm * 128 + 64 + wid * 16 + srow) * K + sslot * 8;
    const u16* pB0 = Bt + (size_t)(bn * 128 +      wid * 16 + srow) * K + sslot * 8;
    const u16* pB1 = Bt + (size_t)(bn * 128 + 64 + wid * 16 + srow) * K + sslot * 8;

    f32x4 acc[4][4] = {};
    const int NT = K >> 5;

    // prologue: stage tile 0 into buf 0
    {
        u16* a0 = (u16*)((char*)As[0] + wid * 1024);
        u16* a1 = (u16*)((char*)As[0] + 4096 + wid * 1024);
        u16* b0 = (u16*)((char*)Bs[0] + wid * 1024);
        u16* b1 = (u16*)((char*)Bs[0] + 4096 + wid * 1024);
        gl2lds16(pA0, a0); gl2lds16(pA1, a1);
        gl2lds16(pB0, b0); gl2lds16(pB1, b1);
    }

    for (int t = 0; t < NT; ++t) {
        const int buf = t & 1;
        if (t + 1 < NT) {
            const int kt1 = (t + 1) << 5;
            u16* a0 = (u16*)((char*)As[buf ^ 1] + wid * 1024);
            u16* a1 = (u16*)((char*)As[buf ^ 1] + 4096 + wid * 1024);
            u16* b0 = (u16*)((char*)Bs[buf ^ 1] + wid * 1024);
            u16* b1 = (u16*)((char*)Bs[buf ^ 1] + 4096 + wid * 1024);
            gl2lds16(pA0 + kt1, a0); gl2lds16(pA1 + kt1, a1);
            gl2lds16(pB0 + kt1, b0); gl2lds16(pB1 + kt1, b1);
            asm volatile("s_waitcnt vmcnt(4)" ::: "memory");
        } else {
            asm volatile("s_waitcnt vmcnt(0)" ::: "memory");
        }
        __builtin_amdgcn_s_barrier();          // tile t visible to all waves
        __builtin_amdgcn_sched_barrier(0);

        s16x8 af[4], bf[4];
        #pragma unroll
        for (int m = 0; m < 4; ++m) {
            int rm = wr * 64 + m * 16 + l15;
            af[m] = *(const s16x8*)((const char*)As[buf] + rm * 64
                                    + ((l4 ^ ((rm >> 1) & 3)) << 4));
        }
        #pragma unroll
        for (int n = 0; n < 4; ++n) {
            int rn = wc * 64 + n * 16 + l15;
            bf[n] = *(const s16x8*)((const char*)Bs[buf] + rn * 64
                                    + ((l4 ^ ((rn >> 1) & 3)) << 4));
        }
        #pragma unroll
        for (int m = 0; m < 4; ++m)
            #pragma unroll
            for (int n = 0; n < 4; ++n)
                acc[m][n] = __builtin_amdgcn_mfma_f32_16x16x32_bf16(
                    af[m], bf[n], acc[m][n], 0, 0, 0);

        // reads of buf complete before next iter's STAGE overwrites it
        asm volatile("s_waitcnt lgkmcnt(0)" ::: "memory");
        __builtin_amdgcn_sched_barrier(0);
        __builtin_amdgcn_s_barrier();
    }

    const int grow0 = bm * 128 + wr * 64;
    const int gcol0 = bn * 128 + wc * 64;
    #pragma unroll
    for (int m = 0; m < 4; ++m) {
        #pragma unroll
        for (int n = 0; n < 4; ++n) {
            int col = gcol0 + n * 16 + l15;
            float bz = bias[col];
            #pragma unroll
            for (int r = 0; r < 4; ++r) {
                int row = grow0 + m * 16 + l4 * 4 + r;
                float v = acc[m][n][r] + bz;
                if constexpr (MODE == 0)
                    outb[(size_t)row * N + col] = f2b(v);
                else
                    outf[(size_t)row * N + col] = v;
            }
        }
    }
}

// ---------------------------------------------------------------------------
// Kernel 3: MFMA windowed attention, stageless (verified R7). Unchanged.
// ---------------------------------------------------------------------------
__global__ __launch_bounds__(256) void attn_mfma_kernel(
    const u16* __restrict__ qkv, const float* __restrict__ emb4,
    u16* __restrict__ att)
{
    __shared__ __align__(16) u16 P4[4][64 * 72];   // 36864 B
    __shared__ int rowIn[64];
    __shared__ int rowOut[64];

    const int tid  = threadIdx.x;
    const int lane = tid & 63;
    const int wid  = tid >> 6;
    const int l15  = lane & 15, l4 = lane >> 4;

    const int blk = blockIdx.x;
    const int hg  = blk % 3;
    const int win = (blk / 3) & 63;
    const int b   = blk / 192;
    const int bw  = win & 7, bh = win >> 3;
    const int head = hg * 4 + wid;

    if (tid < 64) {                                 // roll(-4,-4) gather LUT
        int pix = tid;
        int gr = (bh * 7 + pix / 7 + 4) % IMG;
        int gc = (bw * 7 + pix % 7 + 4) % IMG;
        rowIn[pix] = (b * IMG + gr) * IMG + gc;
    } else if (tid < 128) {                         // roll(+3,+3) scatter LUT
        int q = tid - 64;
        int fr = (bh * 7 + q / 7 + 3) % IMG;
        int fc = (bw * 7 + q % 7 + 3) % IMG;
        rowOut[q] = (b * IMG + fr) * IMG + fc;
    }
    __syncthreads();

    s16x8 qf[4], kf[4];
    #pragma unroll
    for (int n = 0; n < 4; ++n) {
        int pix = n * 16 + l15;
        size_t base = (size_t)rowIn[pix] * NQKV + head * 32 + l4 * 8;
        qf[n] = *(const s16x8*)(qkv + base);          // Q
        kf[n] = *(const s16x8*)(qkv + base + 384);    // K
    }

    f32x4 sc[4][4] = {};
    #pragma unroll
    for (int m = 0; m < 4; ++m)
        #pragma unroll
        for (int n = 0; n < 4; ++n)
            sc[m][n] = __builtin_amdgcn_mfma_f32_16x16x32_bf16(
                kf[m], qf[n], sc[m][n], 0, 0, 0);

    const float scale = 0.17677669529663687f;        // 1/sqrt(32)
    const float* ev = emb4 + ((bh == 7 ? 1 : 0) + (bw == 7 ? 2 : 0)) * 4096;
    u16* P = P4[wid];
    u32* P32 = (u32*)P;

    #pragma unroll
    for (int n = 0; n < 4; ++n) {
        const int q = n * 16 + l15;
        float vals[4][4];
        float mx = -INFINITY;
        #pragma unroll
        for (int m = 0; m < 4; ++m) {
            float4 e4 = *(const float4*)(ev + q * 64 + m * 16 + l4 * 4);
            #pragma unroll
            for (int r = 0; r < 4; ++r) {
                float v = sc[m][n][r] * scale + ((const float*)&e4)[r];
                vals[m][r] = v;
                mx = fmaxf(mx, v);
            }
        }
        mx = fmaxf(mx, __shfl_xor(mx, 16));
        mx = fmaxf(mx, __shfl_xor(mx, 32));
        float sum = 0.f;
        #pragma unroll
        for (int m = 0; m < 4; ++m)
            #pragma unroll
            for (int r = 0; r < 4; ++r) {
                float p = __expf(vals[m][r] - mx);
                vals[m][r] = p;
                sum += p;
            }
        sum += __shfl_xor(sum, 16);
        sum += __shfl_xor(sum, 32);
        float inv = 1.f / sum;
        #pragma unroll
        for (int m = 0; m < 4; ++m) {
            u32 w0 = (u32)f2b(vals[m][0] * inv) | ((u32)f2b(vals[m][1] * inv) << 16);
            u32 w1 = (u32)f2b(vals[m][2] * inv) | ((u32)f2b(vals[m][3] * inv) << 16);
            int bidx = q * 36 + m * 8 + l4 * 2;
            P32[bidx]     = w0;
            P32[bidx + 1] = w1;
        }
    }
    // per-wave private LDS RAW: compiler inserts lgkmcnt waits; no barrier.

    f32x4 o[4][2] = {};
    #pragma unroll
    for (int kh = 0; kh < 2; ++kh) {
        s16x8 pf[4];
        #pragma unroll
        for (int mq = 0; mq < 4; ++mq)
            pf[mq] = *(const s16x8*)&P[(mq * 16 + l15) * 72 + kh * 32 + l4 * 8];
        s16x8 vf[2];
        #pragma unroll
        for (int ne = 0; ne < 2; ++ne) {
            #pragma unroll
            for (int j = 0; j < 8; ++j) {
                int pix = kh * 32 + l4 * 8 + j;
                vf[ne][j] = (short)qkv[(size_t)rowIn[pix] * NQKV + 768
                                       + head * 32 + ne * 16 + l15];
            }
        }
        #pragma unroll
        for (int mq = 0; mq < 4; ++mq)
            #pragma unroll
            for (int ne = 0; ne < 2; ++ne)
                o[mq][ne] = __builtin_amdgcn_mfma_f32_16x16x32_bf16(
                    pf[mq], vf[ne], o[mq][ne], 0, 0, 0);
    }

    #pragma unroll
    for (int mq = 0; mq < 4; ++mq) {
        #pragma unroll
        for (int r = 0; r < 4; ++r) {
            int q = mq * 16 + l4 * 4 + r;
            if (q < 49) {
                size_t rowb = (size_t)rowOut[q] * DIM + head * 32;
                #pragma unroll
                for (int ne = 0; ne < 2; ++ne)
                    att[rowb + ne * 16 + l15] = f2b(o[mq][ne][r]);
            }
        }
    }
}

// ---------------------------------------------------------------------------
extern "C" void kernel_launch(void* const* d_in, const int* in_sizes, int n_in,
                              void* d_out, int out_size, void* d_ws, size_t ws_size,
                              hipStream_t stream) {
    const float* x     = (const float*)d_in[0];
    const float* w_qkv = (const float*)d_in[1];
    const float* b_qkv = (const float*)d_in[2];
    const float* w_out = (const float*)d_in[3];
    const float* b_out = (const float*)d_in[4];
    float* out = (float*)d_out;

    char* wsp = (char*)d_ws;
    float* emb4  = (float*)wsp;                                  // 64 KB
    u16*   wqkvt = (u16*)(wsp + 65536);                          // [1152][384]
    u16*   woutt = (u16*)(wsp + 65536 + 884736);                 // [384][384]
    float* bqkvp = (float*)(wsp + 65536 + 884736 + 294912);      // [1152]
    const size_t fixed = 65536 + 884736 + 294912 + 4608;         // 1,249,792 B

    const size_t perb = (size_t)ROWS_PER_B * (DIM + NQKV + DIM) * 2;
    int nb = 16;
    while (nb > 2 && fixed + (size_t)nb * perb > ws_size) nb >>= 1;

    u16* xb   = (u16*)(wsp + fixed);
    u16* qkvb = xb   + (size_t)nb * ROWS_PER_B * DIM;
    u16* attb = qkvb + (size_t)nb * ROWS_PER_B * NQKV;

    emb4_init_kernel<<<16, 256, 0, stream>>>(emb4);
    cvt_transpose_qkv<<<(384 * 1152 + 255) / 256, 256, 0, stream>>>(w_qkv, wqkvt);
    cvt_transpose_bf16<<<(384 * 384 + 255) / 256, 256, 0, stream>>>(w_out, woutt, 384, 384);
    bias_perm_kernel<<<5, 256, 0, stream>>>(b_qkv, bqkvp);

    for (int b0 = 0; b0 < 16; b0 += nb) {
        const int rows = nb * ROWS_PER_B;
        const float* xa = x + (size_t)b0 * ROWS_PER_B * DIM;

        cvt_f32_bf16<<<(rows * DIM / 4 + 255) / 256, 256, 0, stream>>>(
            xa, xb, rows * DIM / 4);

        mfma_gemm<0><<<dim3(NQKV / 128, rows / 128), 256, 0, stream>>>(
            xb, wqkvt, bqkvp, qkvb, nullptr, NQKV, DIM);

        attn_mfma_kernel<<<nb * 192, 256, 0, stream>>>(qkvb, emb4, attb);

        mfma_gemm<1><<<dim3(DIM / 128, rows / 128), 256, 0, stream>>>(
            attb, woutt, b_out, nullptr, out + (size_t)b0 * ROWS_PER_B * DIM, DIM, DIM);
    }
}